// Round 8
// baseline (105.573 us; speedup 1.0000x reference)
//
#include <hip/hip_runtime.h>
#include <hip/hip_bf16.h>

typedef unsigned short u16;
typedef signed char i8;
typedef __attribute__((ext_vector_type(4))) int   int4v;   // 16 x i8 MFMA A/B frag, or i32x4 C/D
typedef __attribute__((ext_vector_type(4))) float f32x4;

#define GLOBAL_AS __attribute__((address_space(1)))
#define LDS_AS    __attribute__((address_space(3)))

__device__ __forceinline__ void gload_lds16(const void* g, void* l) {
    // 16B/lane direct global->LDS (dest = wave-uniform base + lane*16)
    __builtin_amdgcn_global_load_lds((const GLOBAL_AS unsigned int*)g,
                                     (LDS_AS unsigned int*)l, 16, 0, 0);
}

// ---------------- x: f32 -> i8, per-row symmetric quant; inv_s[row] = rowmax/127 ----------------
__global__ __launch_bounds__(256) void quant_x_kernel(const float* __restrict__ X,
                                                      i8* __restrict__ Xq,
                                                      float* __restrict__ inv_s) {
    const int row = blockIdx.x;
    const int t   = threadIdx.x;
    const float4* src = (const float4*)(X + (size_t)row * 4096 + t * 16);
    float4 v0 = src[0], v1 = src[1], v2 = src[2], v3 = src[3];
    float vals[16] = {v0.x, v0.y, v0.z, v0.w, v1.x, v1.y, v1.z, v1.w,
                      v2.x, v2.y, v2.z, v2.w, v3.x, v3.y, v3.z, v3.w};
    float m = 0.f;
#pragma unroll
    for (int j = 0; j < 16; ++j) m = fmaxf(m, fabsf(vals[j]));
#pragma unroll
    for (int off = 32; off; off >>= 1) m = fmaxf(m, __shfl_xor(m, off));
    __shared__ float sm[4];
    if ((t & 63) == 0) sm[t >> 6] = m;
    __syncthreads();
    m = fmaxf(fmaxf(sm[0], sm[1]), fmaxf(sm[2], sm[3]));
    const float s = (m > 0.f) ? 127.0f / m : 0.f;
    uint4 packed;
    unsigned int* pw = (unsigned int*)&packed;
#pragma unroll
    for (int g = 0; g < 4; ++g) {
        unsigned int wd = 0;
#pragma unroll
        for (int j = 0; j < 4; ++j) {
            int q = (int)rintf(vals[g * 4 + j] * s);   // |q| <= 127 by construction
            wd |= ((unsigned int)(q & 255)) << (8 * j);
        }
        pw[g] = wd;
    }
    ((uint4*)(Xq + (size_t)row * 4096))[t] = packed;
    if (t == 0) inv_s[row] = m * (1.0f / 127.0f);
}

// ---------------- W: f32 [K][N] -> sign i8 (+-1), transposed to [N][K] ----------------
__global__ __launch_bounds__(256) void conv_w_kernel(const float* __restrict__ W,
                                                     i8* __restrict__ Wt) {
    __shared__ __attribute__((aligned(16))) i8 tile[64][80];   // [n_local][k_local], 80 = 5*16
    const int t  = threadIdx.x;
    const int k0 = (blockIdx.x & 63) * 64;
    const int n0 = (blockIdx.x >> 6) * 64;
#pragma unroll
    for (int i = 0; i < 4; ++i) {
        const int r = i * 16 + (t >> 4);      // k_local
        const int c = (t & 15) * 4;           // n_local
        float4 v = *(const float4*)&W[(size_t)(k0 + r) * 4096 + n0 + c];
        tile[c + 0][r] = (v.x >= 0.f) ? 1 : -1;
        tile[c + 1][r] = (v.y >= 0.f) ? 1 : -1;
        tile[c + 2][r] = (v.z >= 0.f) ? 1 : -1;
        tile[c + 3][r] = (v.w >= 0.f) ? 1 : -1;
    }
    __syncthreads();
    const int r = t >> 2;                     // n_local 0..63
    const int c = (t & 3) * 16;               // k_local 16B chunk
    *(int4*)&Wt[(size_t)(n0 + r) * 4096 + k0 + c] = *(const int4*)&tile[r][c];
}

// ---------------- GEMM: i8 128x256 tile, BK=64, 2 blocks/CU (r8) ----------------
// Mechanism change vs r6/r7: the lockstep-barrier 256^2 structure serializes LDS service
// and MFMA (sum, 1 block/CU). Here: 24KB/buffer -> 48KB LDS -> 2 blocks/CU; one block's
// MFMA overlaps the other's LDS/barrier phase (m114 TLP). 4 waves (2M x 2N), per wave
// 64x128 out = acc[4][8]; per K-tile: 12 frag reads + 6 DMA stages per thread-wave.
// Swizzle (64B rows, 128B super-row domain): stored slot s = (c + 4(r&1)) ^ ((r>>1)&7).
// Frag reads land 2 lanes/bank (free). Staging inverse folds to lane consts lin8/sr2/sc.

#define BAR()        __builtin_amdgcn_s_barrier()
#define LGKM0M()     asm volatile("s_waitcnt lgkmcnt(0)" ::: "memory")
#define WAIT_VM6()   asm volatile("s_waitcnt vmcnt(6)" ::: "memory")

// stage one full K-tile (A 128x64B + B 256x64B = 24KB): 6 x gload_lds per thread
#define STAGE_TILE(bufb, koff)                                                      \
    do {                                                                            \
        gload_lds16(AsrcT + (koff),                     lds + (bufb) + wA);         \
        gload_lds16(AsrcT + 65536 + (koff),             lds + (bufb) + wA + 1024);  \
        gload_lds16(BsrcT + (koff),                     lds + (bufb) + 8192 + wB);          \
        gload_lds16(BsrcT + 65536 + (koff),             lds + (bufb) + 8192 + wB + 1024);   \
        gload_lds16(BsrcT + 131072 + (koff),            lds + (bufb) + 8192 + wB + 2048);   \
        gload_lds16(BsrcT + 196608 + (koff),            lds + (bufb) + 8192 + wB + 3072);   \
    } while (0)

__global__ __launch_bounds__(256, 2) void gemm_bin_kernel(const i8* __restrict__ A,
                                                          const i8* __restrict__ Bt,
                                                          const float* __restrict__ bias,
                                                          const float* __restrict__ inv_s,
                                                          float* __restrict__ C) {
    __shared__ __attribute__((aligned(1024))) char lds[49152];   // 2 bufs x (A 8K + B 16K)

    const int bid = blockIdx.x;
    const int swz = (bid & 7) * 64 + (bid >> 3);   // XCD-aware, bijective (512 % 8 == 0)
    const int bm  = swz >> 4;                      // 32 M-tiles (128 rows)
    const int bn  = swz & 15;                      // 16 N-tiles (256 cols)

    const int tid = threadIdx.x;
    const int w   = tid >> 6;
    const int l   = tid & 63;
    const int wm  = w >> 1;                        // 2 M-waves
    const int wn  = w & 1;                         // 2 N-waves

    // ---- staging addressing (inverse-permuted global source, linear LDS dest) ----
    // lane l writes LDS super-row R=(chunk/128)+(l>>3), slot s=l&7; that slot holds
    // logical lin8 = s ^ (R&7) = (l&7)^(l>>3)  (chunk super-rows are multiples of 8).
    const int lin8 = (l & 7) ^ (l >> 3);
    const int sr2  = (l >> 3) * 2 + (lin8 >> 2);   // source row within 16-row chunk
    const int sc   = (lin8 & 3) * 16;              // source col byte within 64B k-slice
    const char* AsrcT = (const char*)A  + (size_t)(bm * 128 + 32 * w + sr2) * 4096 + sc;
    const char* BsrcT = (const char*)Bt + (size_t)(bn * 256 + 64 * w + sr2) * 4096 + sc;
    const int wA = w * 2048;                       // wave's A chunk (rows 32w..32w+31)
    const int wB = w * 4096;                       // wave's B chunk (rows 64w..64w+63)

    // ---- frag read addressing: logical (r = l&15 + 16*frag, c = l>>4) ->
    //      addr = base + (r>>1)*128 + ((c + 4(r&1)) ^ ((r>>1)&7))*16; XOR folds per-thread:
    const int rsl  = ((l >> 4) + 4 * (l & 1)) ^ ((l >> 1) & 7);
    const int a_rd = wm * 4096 + ((l & 15) >> 1) * 128 + rsl * 16;          // + mi*1024
    const int b_rd = 8192 + wn * 8192 + ((l & 15) >> 1) * 128 + rsl * 16;   // + ni*1024

    int4v acc[4][8] = {};
    int4v af[4], bf[8];

    // ---- prologue: stage tile0->buf0, tile1->buf1; land tile0 (tile1's 6 in flight) ----
    STAGE_TILE(0, 0);
    STAGE_TILE(24576, 64);
    WAIT_VM6();
    BAR();

    // ---- main loop: 64 K-tiles of 64 i8 ----
    for (int t = 0; t < 64; ++t) {
        const int bufb  = (t & 1) * 24576;
        const int koff2 = ((t + 2) & 63) * 64;     // wraps to dummy re-stage on last 2 iters

        // frag reads (tile t) — 4 A + 8 B ds_read_b128
#pragma unroll
        for (int mi = 0; mi < 4; ++mi)
            af[mi] = *(const int4v*)(lds + bufb + a_rd + mi * 1024);
#pragma unroll
        for (int ni = 0; ni < 8; ++ni)
            bf[ni] = *(const int4v*)(lds + bufb + b_rd + ni * 1024);
        LGKM0M();                                  // my reads done (WAR guard; "memory" pins ds_reads above)
        BAR();                                     // all reads of buf[t&1] complete block-wide
        STAGE_TILE(bufb, koff2);                   // overwrite buf[t&1] with tile t+2
        WAIT_VM6();                                // tile t+1 landed (t+2's 6 remain in flight)
        BAR();                                     // tile t+1 visible to all

        // MFMA cluster — register-only, free to overlap other block's LDS phases
        __builtin_amdgcn_s_setprio(1);
#pragma unroll
        for (int mi = 0; mi < 4; ++mi)
#pragma unroll
            for (int ni = 0; ni < 8; ++ni)
                acc[mi][ni] = __builtin_amdgcn_mfma_i32_16x16x64_i8(af[mi], bf[ni],
                                                                    acc[mi][ni], 0, 0, 0);
        __builtin_amdgcn_s_setprio(0);
    }
    asm volatile("s_waitcnt vmcnt(0) lgkmcnt(0)" ::: "memory");   // drain DMA before exit

    // ---- epilogue: dequant + bias + ReLU + f32 store (C/D: col=l&15, row=(l>>4)*4+r) ----
    const int col0 = bn * 256 + wn * 128 + (l & 15);
    const int row0 = bm * 128 + wm * 64 + ((l >> 4) << 2);
    float bn8[8];
#pragma unroll
    for (int ni = 0; ni < 8; ++ni) bn8[ni] = bias[col0 + ni * 16];
#pragma unroll
    for (int mi = 0; mi < 4; ++mi) {
#pragma unroll
        for (int r = 0; r < 4; ++r) {
            const int   grow = row0 + mi * 16 + r;
            const float ivs  = inv_s[grow];
#pragma unroll
            for (int ni = 0; ni < 8; ++ni) {
                const float v = (float)acc[mi][ni][r] * ivs + bn8[ni];
                C[(size_t)grow * 4096 + (col0 + ni * 16)] = v > 0.f ? v : 0.f;
            }
        }
    }
}

// ---------------- fallback (only if ws too small): slow but correct ----------------
__global__ __launch_bounds__(256) void fallback_kernel(const float* __restrict__ X,
                                                       const float* __restrict__ W,
                                                       const float* __restrict__ b,
                                                       float* __restrict__ out) {
    __shared__ float xs[16][16];
    __shared__ float ws[16][17];
    const int row = blockIdx.y * 16 + threadIdx.y;
    const int col = blockIdx.x * 16 + threadIdx.x;
    float acc = 0.f;
    for (int k0 = 0; k0 < 4096; k0 += 16) {
        xs[threadIdx.y][threadIdx.x] = X[(size_t)row * 4096 + k0 + threadIdx.x];
        float w = W[(size_t)(k0 + threadIdx.y) * 4096 + col];
        ws[threadIdx.y][threadIdx.x] = (w >= 0.f) ? 1.f : -1.f;
        __syncthreads();
#pragma unroll
        for (int kk = 0; kk < 16; ++kk) acc += xs[threadIdx.y][kk] * ws[kk][threadIdx.x];
        __syncthreads();
    }
    const float v = acc + b[col];
    out[(size_t)row * 4096 + col] = v > 0.f ? v : 0.f;
}

extern "C" void kernel_launch(void* const* d_in, const int* in_sizes, int n_in,
                              void* d_out, int out_size, void* d_ws, size_t ws_size,
                              hipStream_t stream) {
    const float* x = (const float*)d_in[0];
    const float* W = (const float*)d_in[1];
    const float* b = (const float*)d_in[2];
    float* out = (float*)d_out;

    const size_t need = (size_t)32 * 1024 * 1024 + 64 * 1024;   // 2x16MB i8 + 16KB scales
    if (ws_size < need) {
        fallback_kernel<<<dim3(256, 256), dim3(16, 16), 0, stream>>>(x, W, b, out);
        return;
    }

    i8*    Xq  = (i8*)d_ws;                                     // i8 x, [4096][4096]
    i8*    Wt  = Xq + (size_t)4096 * 4096;                      // i8 sign(W)^T, [N][K]
    float* ivs = (float*)(Xq + (size_t)2 * 4096 * 4096);        // per-row inv scale

    quant_x_kernel<<<dim3(4096), dim3(256), 0, stream>>>(x, Xq, ivs);
    conv_w_kernel<<<dim3(4096), dim3(256), 0, stream>>>(W, Wt);
    gemm_bin_kernel<<<dim3(512), dim3(256), 0, stream>>>(Xq, Wt, b, ivs, out);
}

// Round 9
// 97.603 us; speedup vs baseline: 1.0817x; 1.0817x over previous
//
#include <hip/hip_runtime.h>
#include <hip/hip_bf16.h>

typedef unsigned short u16;
typedef signed char i8;
typedef __attribute__((ext_vector_type(4))) int   int4v;   // 16 x i8 MFMA A/B frag, or i32x4 C/D
typedef __attribute__((ext_vector_type(4))) float f32x4;

#define GLOBAL_AS __attribute__((address_space(1)))
#define LDS_AS    __attribute__((address_space(3)))

__device__ __forceinline__ void gload_lds16(const void* g, void* l) {
    // 16B/lane direct global->LDS (dest = wave-uniform base + lane*16)
    __builtin_amdgcn_global_load_lds((const GLOBAL_AS unsigned int*)g,
                                     (LDS_AS unsigned int*)l, 16, 0, 0);
}

// ---------------- x: f32 -> i8, per-row symmetric quant; inv_s[row] = rowmax/127 ----------------
__global__ __launch_bounds__(256) void quant_x_kernel(const float* __restrict__ X,
                                                      i8* __restrict__ Xq,
                                                      float* __restrict__ inv_s) {
    const int row = blockIdx.x;
    const int t   = threadIdx.x;
    const float4* src = (const float4*)(X + (size_t)row * 4096 + t * 16);
    float4 v0 = src[0], v1 = src[1], v2 = src[2], v3 = src[3];
    float vals[16] = {v0.x, v0.y, v0.z, v0.w, v1.x, v1.y, v1.z, v1.w,
                      v2.x, v2.y, v2.z, v2.w, v3.x, v3.y, v3.z, v3.w};
    float m = 0.f;
#pragma unroll
    for (int j = 0; j < 16; ++j) m = fmaxf(m, fabsf(vals[j]));
#pragma unroll
    for (int off = 32; off; off >>= 1) m = fmaxf(m, __shfl_xor(m, off));
    __shared__ float sm[4];
    if ((t & 63) == 0) sm[t >> 6] = m;
    __syncthreads();
    m = fmaxf(fmaxf(sm[0], sm[1]), fmaxf(sm[2], sm[3]));
    const float s = (m > 0.f) ? 127.0f / m : 0.f;
    uint4 packed;
    unsigned int* pw = (unsigned int*)&packed;
#pragma unroll
    for (int g = 0; g < 4; ++g) {
        unsigned int wd = 0;
#pragma unroll
        for (int j = 0; j < 4; ++j) {
            int q = (int)rintf(vals[g * 4 + j] * s);   // |q| <= 127 by construction
            wd |= ((unsigned int)(q & 255)) << (8 * j);
        }
        pw[g] = wd;
    }
    ((uint4*)(Xq + (size_t)row * 4096))[t] = packed;
    if (t == 0) inv_s[row] = m * (1.0f / 127.0f);
}

// ---------------- W: f32 [K][N] -> sign i8 (+-1), transposed to [N][K] ----------------
__global__ __launch_bounds__(256) void conv_w_kernel(const float* __restrict__ W,
                                                     i8* __restrict__ Wt) {
    __shared__ __attribute__((aligned(16))) i8 tile[64][80];   // [n_local][k_local], 80 = 5*16
    const int t  = threadIdx.x;
    const int k0 = (blockIdx.x & 63) * 64;
    const int n0 = (blockIdx.x >> 6) * 64;
#pragma unroll
    for (int i = 0; i < 4; ++i) {
        const int r = i * 16 + (t >> 4);      // k_local
        const int c = (t & 15) * 4;           // n_local
        float4 v = *(const float4*)&W[(size_t)(k0 + r) * 4096 + n0 + c];
        tile[c + 0][r] = (v.x >= 0.f) ? 1 : -1;
        tile[c + 1][r] = (v.y >= 0.f) ? 1 : -1;
        tile[c + 2][r] = (v.z >= 0.f) ? 1 : -1;
        tile[c + 3][r] = (v.w >= 0.f) ? 1 : -1;
    }
    __syncthreads();
    const int r = t >> 2;                     // n_local 0..63
    const int c = (t & 3) * 16;               // k_local 16B chunk
    *(int4*)&Wt[(size_t)(n0 + r) * 4096 + k0 + c] = *(const int4*)&tile[r][c];
}

// ---------------- GEMM: i8 256x256 tile, BK=64, 3-buffer rotation, 1 barrier/K-tile (r9) ----------------
// r6-r8 post-mortems: the 2-buffer lockstep (16 barriers + 8 drains per 2 K-tiles) forces
// LDS service and MFMA to strictly alternate (sum-of-pipes). 3 buffers (96 KB) make the
// stage target a buffer whose readers finished at the PREVIOUS iteration's barrier, so
// intra-iteration barriers vanish: waves free-run, one wave's MFMA overlaps siblings'
// ds_reads (m114). Per iteration: stage(4 gloads, tile t+2) -> 12 frag reads -> 32 MFMA
// (compiler auto-lgkm) -> vmcnt(4) [tile t+1 landed] -> lgkmcnt(0) [rule-18 pin] -> barrier.
// Swizzle: r8-verified 64B-row form (slot = (c + 4(r&1)) ^ ((r>>1)&7)), 0 conflicts.

#define BAR()        __builtin_amdgcn_s_barrier()
#define LGKM0M()     asm volatile("s_waitcnt lgkmcnt(0)" ::: "memory")
#define WAIT_VM4()   asm volatile("s_waitcnt vmcnt(4)" ::: "memory")

// stage one full K-tile (A 256x64B = 16KB + B 256x64B = 16KB): 4 x gload_lds per thread.
// Wave w stages A 16-row chunks {2w,2w+1} and B chunks {2w,2w+1} (1 KB each, linear dest).
#define STAGE_TILE(base, koff)                                                      \
    do {                                                                            \
        gload_lds16(AsrcT + (koff),         lds + (base) + wA);                     \
        gload_lds16(AsrcT + 65536 + (koff), lds + (base) + wA + 1024);              \
        gload_lds16(BsrcT + (koff),         lds + (base) + 16384 + wA);             \
        gload_lds16(BsrcT + 65536 + (koff), lds + (base) + 16384 + wA + 1024);      \
    } while (0)

__global__ __launch_bounds__(512, 2) void gemm_bin_kernel(const i8* __restrict__ A,
                                                          const i8* __restrict__ Bt,
                                                          const float* __restrict__ bias,
                                                          const float* __restrict__ inv_s,
                                                          float* __restrict__ C) {
    __shared__ __attribute__((aligned(1024))) char lds[98304];   // 3 bufs x (A 16K + B 16K)

    const int bid = blockIdx.x;
    const int swz = (bid & 7) * 32 + (bid >> 3);   // XCD-aware, bijective (256 % 8 == 0)
    const int bm  = swz >> 4;                      // 16x16 tiles of 256
    const int bn  = swz & 15;

    const int tid = threadIdx.x;
    const int w   = tid >> 6;
    const int l   = tid & 63;
    const int wm  = w >> 2;                        // 2 M-waves
    const int wn  = w & 3;                         // 4 N-waves

    // ---- staging addressing (inverse-permuted global source, linear LDS dest) ----
    // Lane l writes LDS super-row R = 8q+(l>>3), slot s = l&7; slot s holds logical
    // lin8 = s ^ (R&7) = (l&7)^(l>>3). lin8 -> (r&1, c): r&1 = lin8>>2, c = lin8&3.
    const int lin8 = (l & 7) ^ (l >> 3);
    const int sr2  = (l >> 3) * 2 + (lin8 >> 2);   // source row within 16-row chunk
    const int sc   = (lin8 & 3) * 16;              // source col byte within 64B k-slice
    const char* AsrcT = (const char*)A  + (size_t)(bm * 256 + 32 * w + sr2) * 4096 + sc;
    const char* BsrcT = (const char*)Bt + (size_t)(bn * 256 + 32 * w + sr2) * 4096 + sc;
    const int wA = w * 2048;                       // wave's 2-chunk slice within a region

    // ---- frag read addressing: logical (row = l&15 + 16*frag, col16 = l>>4) ->
    //      byte = region + ((l&15)>>1)*128 + frag*1024 + rsl*16, rsl per-thread const:
    const int rsl  = ((l >> 4) + 4 * (l & 1)) ^ ((l >> 1) & 7);
    const int a_rd = wm * 8192 + ((l & 15) >> 1) * 128 + rsl * 16;           // + mi*1024
    const int b_rd = 16384 + wn * 4096 + ((l & 15) >> 1) * 128 + rsl * 16;   // + ni*1024

    int4v acc[8][4] = {};
    int4v af[8], bf[4];

    // ---- prologue: stage tile0->buf0, tile1->buf1; land tile0 (tile1's 4 in flight) ----
    STAGE_TILE(0, 0);
    STAGE_TILE(32768, 64);
    WAIT_VM4();
    BAR();

    // ---- main loop: 64 K-tiles of 64 i8; 3-buffer rotation, 1 barrier + 1 fence each ----
    int rb = 0;          // buffer holding tile t (read this iter)
    int sb = 65536;      // stage target = buffer read at iter t-1 (free since last barrier)
    for (int t = 0; t < 64; ++t) {
        const int koff2 = ((t + 2) & 63) * 64;     // tile t+2 (wraps to harmless re-stage)

        STAGE_TILE(sb, koff2);                     // DMA issue early; lands 2 iters later

        // frag reads (tile t) — 8 A + 4 B ds_read_b128; compiler inserts fine lgkm waits
#pragma unroll
        for (int mi = 0; mi < 8; ++mi)
            af[mi] = *(const int4v*)(lds + rb + a_rd + mi * 1024);
#pragma unroll
        for (int ni = 0; ni < 4; ++ni)
            bf[ni] = *(const int4v*)(lds + rb + b_rd + ni * 1024);

        __builtin_amdgcn_s_setprio(1);
#pragma unroll
        for (int mi = 0; mi < 8; ++mi)
#pragma unroll
            for (int ni = 0; ni < 4; ++ni)
                acc[mi][ni] = __builtin_amdgcn_mfma_i32_16x16x64_i8(af[mi], bf[ni],
                                                                    acc[mi][ni], 0, 0, 0);
        __builtin_amdgcn_s_setprio(0);

        WAIT_VM4();                                // tile t+1 landed (t+2's 4 stay in flight)
        LGKM0M();                                  // own ds_reads drained (WAR-safe vs DMA)
        BAR();                                     // iteration boundary: frees buf rb
        sb = rb;
        rb = (rb == 65536) ? 0 : rb + 32768;
    }
    asm volatile("s_waitcnt vmcnt(0) lgkmcnt(0)" ::: "memory");   // drain DMA before exit

    // ---- epilogue: dequant + bias + ReLU + f32 store (C/D: col=l&15, row=(l>>4)*4+r) ----
    const int col0 = bn * 256 + wn * 64 + (l & 15);
    const int row0 = bm * 256 + wm * 128 + ((l >> 4) << 2);
    float bn4[4];
#pragma unroll
    for (int n = 0; n < 4; ++n) bn4[n] = bias[col0 + n * 16];
#pragma unroll
    for (int m = 0; m < 8; ++m) {
#pragma unroll
        for (int r = 0; r < 4; ++r) {
            const int   grow = row0 + m * 16 + r;
            const float ivs  = inv_s[grow];
#pragma unroll
            for (int n = 0; n < 4; ++n) {
                const float v = (float)acc[m][n][r] * ivs + bn4[n];
                C[(size_t)grow * 4096 + (col0 + n * 16)] = v > 0.f ? v : 0.f;
            }
        }
    }
}

// ---------------- fallback (only if ws too small): slow but correct ----------------
__global__ __launch_bounds__(256) void fallback_kernel(const float* __restrict__ X,
                                                       const float* __restrict__ W,
                                                       const float* __restrict__ b,
                                                       float* __restrict__ out) {
    __shared__ float xs[16][16];
    __shared__ float ws[16][17];
    const int row = blockIdx.y * 16 + threadIdx.y;
    const int col = blockIdx.x * 16 + threadIdx.x;
    float acc = 0.f;
    for (int k0 = 0; k0 < 4096; k0 += 16) {
        xs[threadIdx.y][threadIdx.x] = X[(size_t)row * 4096 + k0 + threadIdx.x];
        float w = W[(size_t)(k0 + threadIdx.y) * 4096 + col];
        ws[threadIdx.y][threadIdx.x] = (w >= 0.f) ? 1.f : -1.f;
        __syncthreads();
#pragma unroll
        for (int kk = 0; kk < 16; ++kk) acc += xs[threadIdx.y][kk] * ws[kk][threadIdx.x];
        __syncthreads();
    }
    const float v = acc + b[col];
    out[(size_t)row * 4096 + col] = v > 0.f ? v : 0.f;
}

extern "C" void kernel_launch(void* const* d_in, const int* in_sizes, int n_in,
                              void* d_out, int out_size, void* d_ws, size_t ws_size,
                              hipStream_t stream) {
    const float* x = (const float*)d_in[0];
    const float* W = (const float*)d_in[1];
    const float* b = (const float*)d_in[2];
    float* out = (float*)d_out;

    const size_t need = (size_t)32 * 1024 * 1024 + 64 * 1024;   // 2x16MB i8 + 16KB scales
    if (ws_size < need) {
        fallback_kernel<<<dim3(256, 256), dim3(16, 16), 0, stream>>>(x, W, b, out);
        return;
    }

    i8*    Xq  = (i8*)d_ws;                                     // i8 x, [4096][4096]
    i8*    Wt  = Xq + (size_t)4096 * 4096;                      // i8 sign(W)^T, [N][K]
    float* ivs = (float*)(Xq + (size_t)2 * 4096 * 4096);        // per-row inv scale

    quant_x_kernel<<<dim3(4096), dim3(256), 0, stream>>>(x, Xq, ivs);
    conv_w_kernel<<<dim3(4096), dim3(256), 0, stream>>>(W, Wt);
    gemm_bin_kernel<<<dim3(256), dim3(512), 0, stream>>>(Xq, Wt, b, ivs, out);
}